// Round 2
// baseline (444.187 us; speedup 1.0000x reference)
//
#include <hip/hip_runtime.h>
#include <math.h>

// B=256, T=2560, D=128, G=64 groups; sizes cycle 16/32/48/64 per supergroup (160 rows).
// Pairing: (16,64) and (32,48) within a supergroup both total 80 rows = 10 chunks of
// R=8 rows -> every wave does identical work. Grid = 2048 blocks x 4 waves = 8192 waves.
//
// Fully LDS-free: theta stays in the registers of the lane that loaded it; softmax
// weights are made wave-uniform by a shuffle butterfly; each lane accumulates the 4
// output columns it loaded. 3-buffer register rotation keeps one chunk (4 KB/wave)
// in flight for ~2 full iterations.
constexpr int D = 128;
constexpr int B = 256;
constexpr int T = 2560;
constexpr int G = 64;
constexpr int R = 8;   // rows per chunk

template <int J>
__device__ __forceinline__ void run_pair(
    const float4* __restrict__ theta4,  // theta + b*T*D, as float4*
    const float4 s4, const int base, const int h, const int c,
    float* __restrict__ opA, float* __restrict__ opB)
{
    constexpr int NCHA = (J == 0) ? 2 : 4;   // chunks in first group (16 or 32 rows)

    // First row of chunk ch in the flattened 80-row stream:
    //  J==0: rows [base, base+16) then [base+96, base+160)
    //  J==1: rows [base+16, base+96)  (contiguous)
    auto row0 = [&](int ch) -> int {
        return (J == 0) ? (base + ch * R + (ch >= NCHA ? 80 : 0))
                        : (base + 16 + ch * R);
    };

    float4 buf[3][4];
    #pragma unroll
    for (int k = 0; k < 4; ++k)
        buf[0][k] = theta4[(size_t)(row0(0) + 2 * k + h) * 32 + c];
    #pragma unroll
    for (int k = 0; k < 4; ++k)
        buf[1][k] = theta4[(size_t)(row0(1) + 2 * k + h) * 32 + c];

    float m = -INFINITY, l = 0.0f;
    float4 acc = {0.0f, 0.0f, 0.0f, 0.0f};

    #pragma unroll
    for (int ch = 0; ch < 10; ++ch) {
        // prefetch chunk ch+2 into the slot freed at iteration ch-1 (static index)
        if (ch + 2 < 10) {
            #pragma unroll
            for (int k = 0; k < 4; ++k)
                buf[(ch + 2) % 3][k] =
                    theta4[(size_t)(row0(ch + 2) + 2 * k + h) * 32 + c];
        }

        // partial dots: cols 4c..4c+3 of rows 2k+h
        float dt[4];
        #pragma unroll
        for (int k = 0; k < 4; ++k) {
            const float4 v = buf[ch % 3][k];
            dt[k] = v.x * s4.x + v.y * s4.y + v.z * s4.z + v.w * s4.w;
        }
        // butterfly within each 32-lane half: every lane gets full row dots
        #pragma unroll
        for (int k = 0; k < 4; ++k) {
            #pragma unroll
            for (int msk = 16; msk >= 1; msk >>= 1)
                dt[k] += __shfl_xor(dt[k], msk);
            dt[k] *= (1.0f / 128.0f);
        }

        // chunk max over all 8 rows: own 4 + partner half's 4
        float cm = fmaxf(fmaxf(dt[0], dt[1]), fmaxf(dt[2], dt[3]));
        cm = fmaxf(cm, __shfl_xor(cm, 32));
        const float m_new = fmaxf(m, cm);
        const float alpha = __expf(m - m_new);   // 0 on first chunk of a group
        acc.x *= alpha; acc.y *= alpha; acc.z *= alpha; acc.w *= alpha;

        float se = 0.0f;
        #pragma unroll
        for (int k = 0; k < 4; ++k) {
            const float e = __expf(dt[k] - m_new);   // weight of row 2k+h
            se += e;
            const float4 v = buf[ch % 3][k];
            acc.x += e * v.x;
            acc.y += e * v.y;
            acc.z += e * v.z;
            acc.w += e * v.w;
        }
        se += __shfl_xor(se, 32);                    // + partner half's 4 rows
        l = l * alpha + se;
        m = m_new;

        // group boundary (compile-time): merge halves, normalize, store, reset
        if (ch == NCHA - 1 || ch == 9) {
            float4 tot;
            tot.x = acc.x + __shfl_xor(acc.x, 32);
            tot.y = acc.y + __shfl_xor(acc.y, 32);
            tot.z = acc.z + __shfl_xor(acc.z, 32);
            tot.w = acc.w + __shfl_xor(acc.w, 32);
            const float inv_l = 1.0f / l;
            float* op = (ch == NCHA - 1) ? opA : opB;
            if (h == 0) {
                float4 o = {tot.x * inv_l, tot.y * inv_l,
                            tot.z * inv_l, tot.w * inv_l};
                ((float4*)op)[c] = o;                // 512 B coalesced store
            }
            acc = {0.0f, 0.0f, 0.0f, 0.0f};
            m = -INFINITY;
            l = 0.0f;
        }
    }
}

__global__ __launch_bounds__(256, 4) void ragged_attn_pair(
    const float* __restrict__ s_i,     // [B, D]
    const float* __restrict__ theta,   // [B, T, D]
    float* __restrict__ out)           // [B, G, D]
{
    const int w    = threadIdx.x >> 6;      // wave in block: 0..3
    const int lane = threadIdx.x & 63;
    const int sb   = blockIdx.x & 7;        // block covers supergroups 2sb, 2sb+1
    const int b    = blockIdx.x >> 3;

    const int j    = w & 1;                 // 0 -> pair (16,64); 1 -> pair (32,48)
    const int s    = 2 * sb + (w >> 1);     // supergroup for this wave
    const int base = s * 160;

    const int h = lane >> 5;                // row parity within load pair
    const int c = lane & 31;                // float4 column

    const float4 s4 = ((const float4*)(s_i + (size_t)b * D))[c];
    const float4* theta4 = (const float4*)(theta + (size_t)b * T * D);

    if (j == 0)                             // wave-uniform branch
        run_pair<0>(theta4, s4, base, h, c,
                    out + ((size_t)b * G + s * 4 + 0) * D,
                    out + ((size_t)b * G + s * 4 + 3) * D);
    else
        run_pair<1>(theta4, s4, base, h, c,
                    out + ((size_t)b * G + s * 4 + 1) * D,
                    out + ((size_t)b * G + s * 4 + 2) * D);
}

extern "C" void kernel_launch(void* const* d_in, const int* in_sizes, int n_in,
                              void* d_out, int out_size, void* d_ws, size_t ws_size,
                              hipStream_t stream) {
    const float* s_i   = (const float*)d_in[0];
    const float* theta = (const float*)d_in[1];
    float* out = (float*)d_out;

    // 2048 blocks x 256 threads = 8192 waves = B*G/2 group-pairs
    ragged_attn_pair<<<dim3(B * 8), 256, 0, stream>>>(s_i, theta, out);
}